// Round 1
// 808.995 us; speedup vs baseline: 1.2960x; 1.2960x over previous
//
#include <hip/hip_runtime.h>

#define SEQ 512
#define BATCH 4096
#define IND 64
#define HID 128
#define MROWS 16

typedef __attribute__((ext_vector_type(4))) float f32x4;
typedef __attribute__((ext_vector_type(2))) float f32x2;
typedef __attribute__((ext_vector_type(8))) __bf16 bf16x8;
typedef __attribute__((ext_vector_type(2))) __bf16 bf16x2;

__device__ __forceinline__ float tanh_fast(float x) {
    // tanh(x) = 1 - 2/(e^{2x}+1). No clamp needed: e->inf => 1, e->0 => -1.
    float e = __expf(2.f * x);
    return fmaf(-2.f, __builtin_amdgcn_rcpf(e + 1.f), 1.f);
}

// One block = 16 batch rows, persistent across all 512 timesteps.
// 8 waves (512 threads); wave w computes output columns [w*16, w*16+16).
// K = 192 = [x_t (64) | h_{t-1} (128)], mfma_f32_16x16x32_bf16, fp32 accum.
// 2 waves/SIMD so ds_read/MFMA/transcendental latency of one wave overlaps
// the issue of the other (previous version had 1 wave/SIMD: 60% stall).
__global__ __launch_bounds__(512, 2) void rnn_kernel(
    const float* __restrict__ x, const float* __restrict__ Wih,
    const float* __restrict__ bih, const float* __restrict__ Whh,
    const float* __restrict__ bhh, float* __restrict__ out)
{
    // +8 bf16 row pad (16B) keeps ds_read_b128 16B-aligned and breaks
    // the 16-way bank conflict (stride%32dw==4 -> 2-way, free).
    __shared__ __align__(16) __bf16 xs[2][MROWS][72];
    __shared__ __align__(16) __bf16 hs[2][MROWS][136];

    const int tid  = threadIdx.x;
    const int wave = tid >> 6, lane = tid & 63;
    const int quad = lane >> 4, m16 = lane & 15;
    const int nbase = wave * 16;
    const int b0 = blockIdx.x * MROWS;

    // ---- Preload B fragments (combined W^T) into registers ----
    // B[k][n]: n = lane&15 (within this wave's 16-col tile), k = quad*8 + j
    bf16x8 bfrag[6];
    #pragma unroll
    for (int kc = 0; kc < 6; ++kc) {
        const int n  = nbase + m16;
        const int k0 = kc * 32 + quad * 8;
        const float* src = (k0 < IND) ? (Wih + n * IND + k0)
                                      : (Whh + n * HID + (k0 - IND));
        bf16x8 b;
        #pragma unroll
        for (int j = 0; j < 8; ++j) b[j] = (__bf16)src[j];
        bfrag[kc] = b;
    }

    const int n0 = nbase + m16;                 // abs col (C: col=lane&15)
    const float bias = bih[n0] + bhh[n0];
    const f32x4 biasv = {bias, bias, bias, bias};  // folded into MFMA C-init

    // ---- h_0 = 0 ----
    {
        unsigned* hz = (unsigned*)&hs[0][0][0];
        for (int i = tid; i < MROWS * 136 / 2; i += 512) hz[i] = 0u;
    }

    // ---- x staging: each of 512 threads owns one float2 of the 16x64 tile ----
    const int xr = tid >> 5;            // row 0..15
    const int xc = (tid & 31) * 2;      // col 0..62
    const float* xg = x + (size_t)(b0 + xr) * IND + xc;
    const size_t xstep = (size_t)BATCH * IND;

    f32x2 v0     = *(const f32x2*)(xg);          // x_0
    f32x2 pf_cur = *(const f32x2*)(xg + xstep);  // x_1
    {
        bf16x2 w;
        w[0] = (__bf16)v0[0]; w[1] = (__bf16)v0[1];
        *(bf16x2*)&xs[0][xr][xc] = w;
    }
    __syncthreads();

    for (int t = 0; t < SEQ; ++t) {
        const int buf = t & 1;

        // issue prefetch of x_{t+2} (stays in flight across the barrier:
        // raw s_barrier below does NOT drain vmcnt)
        f32x2 pf_nxt;
        if (t + 2 < SEQ) pf_nxt = *(const f32x2*)(xg + (size_t)(t + 2) * xstep);

        // ---- A fragments: A[m=lane&15][k=quad*8+j] ----
        bf16x8 af[6];
        const __bf16* xp = &xs[buf][0][0] + m16 * 72  + quad * 8;
        const __bf16* hp = &hs[buf][0][0] + m16 * 136 + quad * 8;
        #pragma unroll
        for (int kc = 0; kc < 2; ++kc) af[kc]     = *(const bf16x8*)(xp + kc * 32);
        #pragma unroll
        for (int kc = 0; kc < 4; ++kc) af[2 + kc] = *(const bf16x8*)(hp + kc * 32);

        f32x4 acc = biasv;
        #pragma unroll
        for (int kc = 0; kc < 6; ++kc)
            acc = __builtin_amdgcn_mfma_f32_16x16x32_bf16(af[kc], bfrag[kc], acc, 0, 0, 0);

        // ---- stage x_{t+1} into the other buffer ----
        if (t + 1 < SEQ) {
            bf16x2 w;
            w[0] = (__bf16)pf_cur[0]; w[1] = (__bf16)pf_cur[1];
            *(bf16x2*)&xs[buf ^ 1][xr][xc] = w;
        }

        // ---- epilogue: tanh (bias already in acc); C: col=lane&15, row=quad*4+r ----
        if (t == SEQ - 1) {
            #pragma unroll
            for (int r = 0; r < 4; ++r) {
                const int row = quad * 4 + r;
                out[(size_t)(b0 + row) * HID + n0] = tanh_fast(acc[r]);
            }
        } else {
            __bf16* hw = &hs[buf ^ 1][0][0];
            #pragma unroll
            for (int r = 0; r < 4; ++r) {
                const int row = quad * 4 + r;
                hw[row * 136 + n0] = (__bf16)tanh_fast(acc[r]);
            }
        }

        if (t + 2 < SEQ) pf_cur = pf_nxt;

        // LDS-only barrier: drain DS ops, leave the global prefetch in flight.
        __asm__ __volatile__("s_waitcnt lgkmcnt(0)\n\ts_barrier" ::: "memory");
    }
}

extern "C" void kernel_launch(void* const* d_in, const int* in_sizes, int n_in,
                              void* d_out, int out_size, void* d_ws, size_t ws_size,
                              hipStream_t stream) {
    const float* x   = (const float*)d_in[0];
    const float* Wih = (const float*)d_in[1];
    const float* bih = (const float*)d_in[2];
    const float* Whh = (const float*)d_in[3];
    const float* bhh = (const float*)d_in[4];
    float* out = (float*)d_out;

    dim3 grid(BATCH / MROWS);   // 256 blocks, 16 batch rows each
    dim3 block(512);            // 8 waves, 2 per SIMD
    hipLaunchKernelGGL(rnn_kernel, grid, block, 0, stream, x, Wih, bih, Whh, bhh, out);
}